// Round 7
// baseline (138.844 us; speedup 1.0000x reference)
//
#include <hip/hip_runtime.h>

// LQActiv forward: 2-bit quantization + least-squares basis refit.
// Output layout: [N floats wq][2 floats new_basis].
//
// Round 7: single-variable A/B vs round 6 — stores CACHED (L2 write-allocate
// merges full lines), loads stay NT. Round 6 fixed the scratch spill
// (249->133us) but WRITE_SIZE sits at 233MB = 2.26x ideal with BW pinned at
// 2.3 TB/s; theory: NT stores bypass L2's merge path and hit HBM as
// sub-line granules (padding/RMW ~2.26x + wasted bus slots).
//
// Kernel 1 (lq_main): lean web — {Q0..Q3,T0..T2} + 7 raw accumulators;
//   encoding algebra deferred to lq_final via telescoped sums.
// Kernel 2 (lq_final): f64 reduce of nblocks*7 partials, 2x2 solve.

#define NBLOCKS 2048
#define NTHREADS 256

typedef float fvec4 __attribute__((ext_vector_type(4)));

__global__ __launch_bounds__(NTHREADS) void lq_main(
    const float* __restrict__ x, const float* __restrict__ basis,
    float* __restrict__ out, float* __restrict__ partials,
    int n, int n4, int nblocks) {
  // sorted quantization levels (values only; encodings not needed here)
  const float v0 = basis[0], v1 = basis[1];
  float lev[4] = {-v0 - v1, -v0 + v1, v0 - v1, v0 + v1};
#define CSWAP(i, j)                                          \
  if (lev[i] > lev[j]) { float t = lev[i]; lev[i] = lev[j]; lev[j] = t; }
  CSWAP(0, 1) CSWAP(2, 3) CSWAP(0, 2) CSWAP(1, 3) CSWAP(1, 2)
#undef CSWAP
  const float Q0 = lev[0], Q1 = lev[1], Q2 = lev[2], Q3 = lev[3];
  const float T0 = 0.5f * (Q0 + Q1);
  const float T1 = 0.5f * (Q1 + Q2);
  const float T2 = 0.5f * (Q2 + Q3);

  int c0 = 0, c1 = 0, c2 = 0;
  float sw = 0.f, sw0 = 0.f, sw1 = 0.f, sw2 = 0.f;

  auto proc = [&](float w) -> float {
    const bool t0 = w > T0;
    const bool t1 = w > T1;
    const bool t2 = w > T2;
    c0 += t0;
    c1 += t1;
    c2 += t2;
    sw += w;
    sw0 += t0 ? w : 0.f;
    sw1 += t1 ? w : 0.f;
    sw2 += t2 ? w : 0.f;
    float q = t0 ? Q1 : Q0;   // thresholds monotone: q = Qlevels[t0+t1+t2]
    q = t1 ? Q2 : q;
    q = t2 ? Q3 : q;
    return q;
  };

  const fvec4* __restrict__ x4 = (const fvec4*)x;
  fvec4* __restrict__ o4 = (fvec4*)out;

  const int tid = blockIdx.x * blockDim.x + threadIdx.x;
  const int stride = gridDim.x * blockDim.x;

  // NT load (read-once stream), CACHED store (L2 line-merge) <- the A/B
  for (int i = tid; i < n4; i += stride) {
    fvec4 w = __builtin_nontemporal_load(&x4[i]);
    fvec4 q;
    q.x = proc(w.x);
    q.y = proc(w.y);
    q.z = proc(w.z);
    q.w = proc(w.w);
    o4[i] = q;
  }
  // scalar tail (N divisible by 4; kept for safety)
  for (int k = n4 * 4 + tid; k < n; k += stride) {
    out[k] = proc(x[k]);
  }

  // block reduction: wave shfl, then LDS across the 4 waves
  float f0 = (float)c0, f1 = (float)c1, f2 = (float)c2;
  for (int off = 32; off; off >>= 1) {
    f0 += __shfl_down(f0, off);
    f1 += __shfl_down(f1, off);
    f2 += __shfl_down(f2, off);
    sw += __shfl_down(sw, off);
    sw0 += __shfl_down(sw0, off);
    sw1 += __shfl_down(sw1, off);
    sw2 += __shfl_down(sw2, off);
  }
  __shared__ float red[7][NTHREADS / 64];
  const int lane = threadIdx.x & 63;
  const int wid = threadIdx.x >> 6;
  if (lane == 0) {
    red[0][wid] = f0;
    red[1][wid] = f1;
    red[2][wid] = f2;
    red[3][wid] = sw;
    red[4][wid] = sw0;
    red[5][wid] = sw1;
    red[6][wid] = sw2;
  }
  __syncthreads();
  if (threadIdx.x < 7) {
    float r = 0.f;
#pragma unroll
    for (int w = 0; w < NTHREADS / 64; ++w) r += red[threadIdx.x][w];
    partials[7 * blockIdx.x + threadIdx.x] = r;
  }
}

__global__ __launch_bounds__(NTHREADS) void lq_final(
    const float* __restrict__ partials, const float* __restrict__ basis,
    float* __restrict__ out_basis, int n, int nparts) {
  double C0 = 0, C1 = 0, C2 = 0, SW = 0, SW0 = 0, SW1 = 0, SW2 = 0;
  for (int i = threadIdx.x; i < nparts; i += blockDim.x) {
    C0 += (double)partials[7 * i + 0];
    C1 += (double)partials[7 * i + 1];
    C2 += (double)partials[7 * i + 2];
    SW += (double)partials[7 * i + 3];
    SW0 += (double)partials[7 * i + 4];
    SW1 += (double)partials[7 * i + 5];
    SW2 += (double)partials[7 * i + 6];
  }
  for (int off = 32; off; off >>= 1) {
    C0 += __shfl_down(C0, off);
    C1 += __shfl_down(C1, off);
    C2 += __shfl_down(C2, off);
    SW += __shfl_down(SW, off);
    SW0 += __shfl_down(SW0, off);
    SW1 += __shfl_down(SW1, off);
    SW2 += __shfl_down(SW2, off);
  }
  __shared__ double red[7][NTHREADS / 64];
  const int lane = threadIdx.x & 63;
  const int wid = threadIdx.x >> 6;
  if (lane == 0) {
    red[0][wid] = C0;
    red[1][wid] = C1;
    red[2][wid] = C2;
    red[3][wid] = SW;
    red[4][wid] = SW0;
    red[5][wid] = SW1;
    red[6][wid] = SW2;
  }
  __syncthreads();
  if (threadIdx.x == 0) {
    double c0 = 0, c1 = 0, c2 = 0, s = 0, s0 = 0, s1 = 0, s2 = 0;
#pragma unroll
    for (int w = 0; w < NTHREADS / 64; ++w) {
      c0 += red[0][w];
      c1 += red[1][w];
      c2 += red[2][w];
      s += red[3][w];
      s0 += red[4][w];
      s1 += red[5][w];
      s2 += red[6][w];
    }
    // re-derive sorted levels + encodings from basis
    const float v0 = basis[0], v1 = basis[1];
    float lev[4] = {-v0 - v1, -v0 + v1, v0 - v1, v0 + v1};
    float e0[4] = {-1.f, -1.f, 1.f, 1.f};
    float e1[4] = {-1.f, 1.f, -1.f, 1.f};
#define CSWAP(i, j)                                                   \
    if (lev[i] > lev[j]) {                                            \
      float t = lev[i]; lev[i] = lev[j]; lev[j] = t;                  \
      t = e0[i]; e0[i] = e0[j]; e0[j] = t;                            \
      t = e1[i]; e1[i] = e1[j]; e1[j] = t;                            \
    }
    CSWAP(0, 1) CSWAP(2, 3) CSWAP(0, 2) CSWAP(1, 3) CSWAP(1, 2)
#undef CSWAP
    const double A0 = e0[0], A1 = e0[1], A2 = e0[2], A3 = e0[3];
    const double B0 = e1[0], B1 = e1[1], B2 = e1[2], B3 = e1[3];
    const double N = (double)n;
    // telescoped sums over the monotone one-hot
    const double Sb0 = A0 * s + (A1 - A0) * s0 + (A2 - A1) * s1 + (A3 - A2) * s2;
    const double Sb1 = B0 * s + (B1 - B0) * s0 + (B2 - B1) * s1 + (B3 - B2) * s2;
    const double P0 = A0 * B0, P1 = A1 * B1, P2 = A2 * B2, P3 = A3 * B3;
    const double S01 = P0 * N + (P1 - P0) * c0 + (P2 - P1) * c1 + (P3 - P2) * c2;
    const double det = N * N - S01 * S01;
    const double nv0 = (N * Sb0 - S01 * Sb1) / det;
    const double nv1 = (N * Sb1 - S01 * Sb0) / det;
    out_basis[0] = (float)(0.9 * (double)v0 + 0.1 * nv0);
    out_basis[1] = (float)(0.9 * (double)v1 + 0.1 * nv1);
  }
}

extern "C" void kernel_launch(void* const* d_in, const int* in_sizes, int n_in,
                              void* d_out, int out_size, void* d_ws, size_t ws_size,
                              hipStream_t stream) {
  const float* x = (const float*)d_in[0];
  const float* basis = (const float*)d_in[1];
  float* out = (float*)d_out;
  const int n = in_sizes[0];
  float* partials = (float*)d_ws;  // nblocks * 7 floats

  int nblocks = NBLOCKS;
  const int maxb = (int)(ws_size / (7 * sizeof(float)));
  if (nblocks > maxb) nblocks = maxb;
  if (nblocks < 1) nblocks = 1;

  const int n4 = n / 4;
  lq_main<<<nblocks, NTHREADS, 0, stream>>>(x, basis, out, partials, n, n4, nblocks);
  lq_final<<<1, NTHREADS, 0, stream>>>(partials, basis, out + n, n, nblocks);
}

// Round 8
// 99.301 us; speedup vs baseline: 1.3982x; 1.3982x over previous
//
#include <hip/hip_runtime.h>

// LQActiv forward: 2-bit quantization + least-squares basis refit.
// Output layout: [N floats wq][2 floats new_basis].
//
// Round 8: SPLIT into the two shapes proven fast in-situ by round-5 probes.
// The fused kernel is pinned at 2.3 TB/s (135us) while a copy (33us) and a
// read-reduce (15us) with identical instructions run at ~6.4 TB/s. The
// quantized output depends only on basis (thresholds/levels), NOT on the
// stats, so the two streams separate cleanly:
//   K1 lq_stats: reduce-shaped. NT reads, 7 accumulators, writes only
//      7 floats/block of partials. No output stream.
//   K2 lq_quant: copy-shaped. NT read -> 6-op select chain -> NT store.
//      Zero accumulators, zero loop-carried deps.
//   K3 lq_final: f64 reduce of partials, telescoped encoding algebra,
//      2x2 solve -> new_basis.

#define NBLOCKS 2048
#define NTHREADS 256

typedef float fvec4 __attribute__((ext_vector_type(4)));

// ---- K1: stats only (reduce_probe shape) ----
__global__ __launch_bounds__(NTHREADS) void lq_stats(
    const float* __restrict__ x, const float* __restrict__ basis,
    float* __restrict__ partials, int n4) {
  const float v0 = basis[0], v1 = basis[1];
  float lev[4] = {-v0 - v1, -v0 + v1, v0 - v1, v0 + v1};
#define CSWAP(i, j)                                          \
  if (lev[i] > lev[j]) { float t = lev[i]; lev[i] = lev[j]; lev[j] = t; }
  CSWAP(0, 1) CSWAP(2, 3) CSWAP(0, 2) CSWAP(1, 3) CSWAP(1, 2)
#undef CSWAP
  // stats need only the thresholds (3 uniforms), not the levels
  const float T0 = 0.5f * (lev[0] + lev[1]);
  const float T1 = 0.5f * (lev[1] + lev[2]);
  const float T2 = 0.5f * (lev[2] + lev[3]);

  int c0 = 0, c1 = 0, c2 = 0;
  float sw = 0.f, sw0 = 0.f, sw1 = 0.f, sw2 = 0.f;

  auto acc = [&](float w) {
    const bool t0 = w > T0;
    const bool t1 = w > T1;
    const bool t2 = w > T2;
    c0 += t0;
    c1 += t1;
    c2 += t2;
    sw += w;
    sw0 += t0 ? w : 0.f;
    sw1 += t1 ? w : 0.f;
    sw2 += t2 ? w : 0.f;
  };

  const fvec4* __restrict__ x4 = (const fvec4*)x;
  const int tid = blockIdx.x * blockDim.x + threadIdx.x;
  const int stride = gridDim.x * blockDim.x;
  for (int i = tid; i < n4; i += stride) {
    fvec4 w = __builtin_nontemporal_load(&x4[i]);
    acc(w.x);
    acc(w.y);
    acc(w.z);
    acc(w.w);
  }

  float f0 = (float)c0, f1 = (float)c1, f2 = (float)c2;
  for (int off = 32; off; off >>= 1) {
    f0 += __shfl_down(f0, off);
    f1 += __shfl_down(f1, off);
    f2 += __shfl_down(f2, off);
    sw += __shfl_down(sw, off);
    sw0 += __shfl_down(sw0, off);
    sw1 += __shfl_down(sw1, off);
    sw2 += __shfl_down(sw2, off);
  }
  __shared__ float red[7][NTHREADS / 64];
  const int lane = threadIdx.x & 63;
  const int wid = threadIdx.x >> 6;
  if (lane == 0) {
    red[0][wid] = f0;
    red[1][wid] = f1;
    red[2][wid] = f2;
    red[3][wid] = sw;
    red[4][wid] = sw0;
    red[5][wid] = sw1;
    red[6][wid] = sw2;
  }
  __syncthreads();
  if (threadIdx.x < 7) {
    float r = 0.f;
#pragma unroll
    for (int w = 0; w < NTHREADS / 64; ++w) r += red[threadIdx.x][w];
    partials[7 * blockIdx.x + threadIdx.x] = r;
  }
}

// ---- K2: quantize only (copy_probe shape; no accumulators) ----
__global__ __launch_bounds__(NTHREADS) void lq_quant(
    const float* __restrict__ x, const float* __restrict__ basis,
    float* __restrict__ out, int n, int n4) {
  const float v0 = basis[0], v1 = basis[1];
  float lev[4] = {-v0 - v1, -v0 + v1, v0 - v1, v0 + v1};
#define CSWAP(i, j)                                          \
  if (lev[i] > lev[j]) { float t = lev[i]; lev[i] = lev[j]; lev[j] = t; }
  CSWAP(0, 1) CSWAP(2, 3) CSWAP(0, 2) CSWAP(1, 3) CSWAP(1, 2)
#undef CSWAP
  const float Q0 = lev[0], Q1 = lev[1], Q2 = lev[2], Q3 = lev[3];
  const float T0 = 0.5f * (Q0 + Q1);
  const float T1 = 0.5f * (Q1 + Q2);
  const float T2 = 0.5f * (Q2 + Q3);

  auto quant = [&](float w) -> float {
    float q = (w > T0) ? Q1 : Q0;  // thresholds monotone:
    q = (w > T1) ? Q2 : q;         // q = Qlevels[(w>T0)+(w>T1)+(w>T2)]
    q = (w > T2) ? Q3 : q;
    return q;
  };

  const fvec4* __restrict__ x4 = (const fvec4*)x;
  fvec4* __restrict__ o4 = (fvec4*)out;
  const int tid = blockIdx.x * blockDim.x + threadIdx.x;
  const int stride = gridDim.x * blockDim.x;
  for (int i = tid; i < n4; i += stride) {
    fvec4 w = __builtin_nontemporal_load(&x4[i]);
    fvec4 q;
    q.x = quant(w.x);
    q.y = quant(w.y);
    q.z = quant(w.z);
    q.w = quant(w.w);
    __builtin_nontemporal_store(q, &o4[i]);
  }
  for (int k = n4 * 4 + tid; k < n; k += stride) {
    out[k] = quant(x[k]);
  }
}

// ---- K3: final reduce + 2x2 solve ----
__global__ __launch_bounds__(NTHREADS) void lq_final(
    const float* __restrict__ partials, const float* __restrict__ basis,
    float* __restrict__ out_basis, int n, int nparts) {
  double C0 = 0, C1 = 0, C2 = 0, SW = 0, SW0 = 0, SW1 = 0, SW2 = 0;
  for (int i = threadIdx.x; i < nparts; i += blockDim.x) {
    C0 += (double)partials[7 * i + 0];
    C1 += (double)partials[7 * i + 1];
    C2 += (double)partials[7 * i + 2];
    SW += (double)partials[7 * i + 3];
    SW0 += (double)partials[7 * i + 4];
    SW1 += (double)partials[7 * i + 5];
    SW2 += (double)partials[7 * i + 6];
  }
  for (int off = 32; off; off >>= 1) {
    C0 += __shfl_down(C0, off);
    C1 += __shfl_down(C1, off);
    C2 += __shfl_down(C2, off);
    SW += __shfl_down(SW, off);
    SW0 += __shfl_down(SW0, off);
    SW1 += __shfl_down(SW1, off);
    SW2 += __shfl_down(SW2, off);
  }
  __shared__ double red[7][NTHREADS / 64];
  const int lane = threadIdx.x & 63;
  const int wid = threadIdx.x >> 6;
  if (lane == 0) {
    red[0][wid] = C0;
    red[1][wid] = C1;
    red[2][wid] = C2;
    red[3][wid] = SW;
    red[4][wid] = SW0;
    red[5][wid] = SW1;
    red[6][wid] = SW2;
  }
  __syncthreads();
  if (threadIdx.x == 0) {
    double c0 = 0, c1 = 0, c2 = 0, s = 0, s0 = 0, s1 = 0, s2 = 0;
#pragma unroll
    for (int w = 0; w < NTHREADS / 64; ++w) {
      c0 += red[0][w];
      c1 += red[1][w];
      c2 += red[2][w];
      s += red[3][w];
      s0 += red[4][w];
      s1 += red[5][w];
      s2 += red[6][w];
    }
    // re-derive sorted levels + encodings from basis
    const float v0 = basis[0], v1 = basis[1];
    float lev[4] = {-v0 - v1, -v0 + v1, v0 - v1, v0 + v1};
    float e0[4] = {-1.f, -1.f, 1.f, 1.f};
    float e1[4] = {-1.f, 1.f, -1.f, 1.f};
#define CSWAP(i, j)                                                   \
    if (lev[i] > lev[j]) {                                            \
      float t = lev[i]; lev[i] = lev[j]; lev[j] = t;                  \
      t = e0[i]; e0[i] = e0[j]; e0[j] = t;                            \
      t = e1[i]; e1[i] = e1[j]; e1[j] = t;                            \
    }
    CSWAP(0, 1) CSWAP(2, 3) CSWAP(0, 2) CSWAP(1, 3) CSWAP(1, 2)
#undef CSWAP
    const double A0 = e0[0], A1 = e0[1], A2 = e0[2], A3 = e0[3];
    const double B0 = e1[0], B1 = e1[1], B2 = e1[2], B3 = e1[3];
    const double N = (double)n;
    // telescoped sums over the monotone one-hot:
    //   sum f(idx)   = f(0)*N + [f(1)-f(0)]*C0 + [f(2)-f(1)]*C1 + [f(3)-f(2)]*C2
    //   sum f(idx)*w = f(0)*SW + ... with SW0..SW2
    const double Sb0 = A0 * s + (A1 - A0) * s0 + (A2 - A1) * s1 + (A3 - A2) * s2;
    const double Sb1 = B0 * s + (B1 - B0) * s0 + (B2 - B1) * s1 + (B3 - B2) * s2;
    const double P0 = A0 * B0, P1 = A1 * B1, P2 = A2 * B2, P3 = A3 * B3;
    const double S01 = P0 * N + (P1 - P0) * c0 + (P2 - P1) * c1 + (P3 - P2) * c2;
    const double det = N * N - S01 * S01;
    const double nv0 = (N * Sb0 - S01 * Sb1) / det;
    const double nv1 = (N * Sb1 - S01 * Sb0) / det;
    out_basis[0] = (float)(0.9 * (double)v0 + 0.1 * nv0);
    out_basis[1] = (float)(0.9 * (double)v1 + 0.1 * nv1);
  }
}

extern "C" void kernel_launch(void* const* d_in, const int* in_sizes, int n_in,
                              void* d_out, int out_size, void* d_ws, size_t ws_size,
                              hipStream_t stream) {
  const float* x = (const float*)d_in[0];
  const float* basis = (const float*)d_in[1];
  float* out = (float*)d_out;
  const int n = in_sizes[0];
  float* partials = (float*)d_ws;  // nblocks * 7 floats

  int nblocks = NBLOCKS;
  const int maxb = (int)(ws_size / (7 * sizeof(float)));
  if (nblocks > maxb) nblocks = maxb;
  if (nblocks < 1) nblocks = 1;

  const int n4 = n / 4;
  lq_stats<<<nblocks, NTHREADS, 0, stream>>>(x, basis, partials, n4);
  lq_quant<<<NBLOCKS, NTHREADS, 0, stream>>>(x, basis, out, n, n4);
  lq_final<<<1, NTHREADS, 0, stream>>>(partials, basis, out + n, n, nblocks);
}

// Round 9
// 94.861 us; speedup vs baseline: 1.4637x; 1.0468x over previous
//
#include <hip/hip_runtime.h>

// LQActiv forward: 2-bit quantization + least-squares basis refit.
// Output layout: [N floats wq][2 floats new_basis].
//
// Round 9: deepen lq_quant's memory pipeline. Round 8 proved the split
// works (stats ~20us ~= read roofline; WRITE amplification gone), but
// lq_quant (VGPR=12, 1-deep loop) runs 74.7us vs the 33us copy probe:
// one load in flight per wave + 24 dependent VALU ops between load-return
// and store halves the sustained memory request rate. Fix: 4 independent
// NT loads in flight per iteration (block-tiled 4KB/wave-quad), one wait,
// 16 selects, 4 NT stores. No accumulators -> no spill web (round-4's
// failure mode is gone).
//
//   K1 lq_stats: reduce-shaped. NT reads, 7 accumulators, 7 floats/block.
//   K2 lq_quant: copy-shaped, 4-deep. NT read -> select chain -> NT store.
//   K3 lq_final: f64 reduce + telescoped encoding algebra + 2x2 solve.

#define NBLOCKS 2048
#define NTHREADS 256
#define QVEC 4  // fvec4 per thread per lq_quant iteration

typedef float fvec4 __attribute__((ext_vector_type(4)));

// ---- K1: stats only (reduce_probe shape) — unchanged from round 8 ----
__global__ __launch_bounds__(NTHREADS) void lq_stats(
    const float* __restrict__ x, const float* __restrict__ basis,
    float* __restrict__ partials, int n4) {
  const float v0 = basis[0], v1 = basis[1];
  float lev[4] = {-v0 - v1, -v0 + v1, v0 - v1, v0 + v1};
#define CSWAP(i, j)                                          \
  if (lev[i] > lev[j]) { float t = lev[i]; lev[i] = lev[j]; lev[j] = t; }
  CSWAP(0, 1) CSWAP(2, 3) CSWAP(0, 2) CSWAP(1, 3) CSWAP(1, 2)
#undef CSWAP
  const float T0 = 0.5f * (lev[0] + lev[1]);
  const float T1 = 0.5f * (lev[1] + lev[2]);
  const float T2 = 0.5f * (lev[2] + lev[3]);

  int c0 = 0, c1 = 0, c2 = 0;
  float sw = 0.f, sw0 = 0.f, sw1 = 0.f, sw2 = 0.f;

  auto acc = [&](float w) {
    const bool t0 = w > T0;
    const bool t1 = w > T1;
    const bool t2 = w > T2;
    c0 += t0;
    c1 += t1;
    c2 += t2;
    sw += w;
    sw0 += t0 ? w : 0.f;
    sw1 += t1 ? w : 0.f;
    sw2 += t2 ? w : 0.f;
  };

  const fvec4* __restrict__ x4 = (const fvec4*)x;
  const int tid = blockIdx.x * blockDim.x + threadIdx.x;
  const int stride = gridDim.x * blockDim.x;
  for (int i = tid; i < n4; i += stride) {
    fvec4 w = __builtin_nontemporal_load(&x4[i]);
    acc(w.x);
    acc(w.y);
    acc(w.z);
    acc(w.w);
  }

  float f0 = (float)c0, f1 = (float)c1, f2 = (float)c2;
  for (int off = 32; off; off >>= 1) {
    f0 += __shfl_down(f0, off);
    f1 += __shfl_down(f1, off);
    f2 += __shfl_down(f2, off);
    sw += __shfl_down(sw, off);
    sw0 += __shfl_down(sw0, off);
    sw1 += __shfl_down(sw1, off);
    sw2 += __shfl_down(sw2, off);
  }
  __shared__ float red[7][NTHREADS / 64];
  const int lane = threadIdx.x & 63;
  const int wid = threadIdx.x >> 6;
  if (lane == 0) {
    red[0][wid] = f0;
    red[1][wid] = f1;
    red[2][wid] = f2;
    red[3][wid] = sw;
    red[4][wid] = sw0;
    red[5][wid] = sw1;
    red[6][wid] = sw2;
  }
  __syncthreads();
  if (threadIdx.x < 7) {
    float r = 0.f;
#pragma unroll
    for (int w = 0; w < NTHREADS / 64; ++w) r += red[threadIdx.x][w];
    partials[7 * blockIdx.x + threadIdx.x] = r;
  }
}

// ---- K2: quantize only, 4-deep MLP (this round's single variable) ----
__global__ __launch_bounds__(NTHREADS) void lq_quant(
    const float* __restrict__ x, const float* __restrict__ basis,
    float* __restrict__ out, int n, int n4) {
  const float v0 = basis[0], v1 = basis[1];
  float lev[4] = {-v0 - v1, -v0 + v1, v0 - v1, v0 + v1};
#define CSWAP(i, j)                                          \
  if (lev[i] > lev[j]) { float t = lev[i]; lev[i] = lev[j]; lev[j] = t; }
  CSWAP(0, 1) CSWAP(2, 3) CSWAP(0, 2) CSWAP(1, 3) CSWAP(1, 2)
#undef CSWAP
  const float Q0 = lev[0], Q1 = lev[1], Q2 = lev[2], Q3 = lev[3];
  const float T0 = 0.5f * (Q0 + Q1);
  const float T1 = 0.5f * (Q1 + Q2);
  const float T2 = 0.5f * (Q2 + Q3);

  auto quant = [&](float w) -> float {
    float q = (w > T0) ? Q1 : Q0;  // thresholds monotone:
    q = (w > T1) ? Q2 : q;         // q = Qlevels[(w>T0)+(w>T1)+(w>T2)]
    q = (w > T2) ? Q3 : q;
    return q;
  };
  auto quant4 = [&](fvec4 w) -> fvec4 {
    fvec4 q;
    q.x = quant(w.x);
    q.y = quant(w.y);
    q.z = quant(w.z);
    q.w = quant(w.w);
    return q;
  };

  const fvec4* __restrict__ x4 = (const fvec4*)x;
  fvec4* __restrict__ o4 = (fvec4*)out;

  const int grid_tile = NBLOCKS * NTHREADS * QVEC;  // vec4 per grid pass
  const int nfull = n4 / grid_tile;                 // compile-time divisor
  const int rem_start = nfull * grid_tile;

  for (int j = 0; j < nfull; ++j) {
    const int base = j * grid_tile + blockIdx.x * (NTHREADS * QVEC) + threadIdx.x;
    // 4 independent NT loads in flight before any use
    fvec4 w0 = __builtin_nontemporal_load(&x4[base + 0 * NTHREADS]);
    fvec4 w1 = __builtin_nontemporal_load(&x4[base + 1 * NTHREADS]);
    fvec4 w2 = __builtin_nontemporal_load(&x4[base + 2 * NTHREADS]);
    fvec4 w3 = __builtin_nontemporal_load(&x4[base + 3 * NTHREADS]);
    fvec4 q0 = quant4(w0);
    fvec4 q1 = quant4(w1);
    fvec4 q2 = quant4(w2);
    fvec4 q3 = quant4(w3);
    __builtin_nontemporal_store(q0, &o4[base + 0 * NTHREADS]);
    __builtin_nontemporal_store(q1, &o4[base + 1 * NTHREADS]);
    __builtin_nontemporal_store(q2, &o4[base + 2 * NTHREADS]);
    __builtin_nontemporal_store(q3, &o4[base + 3 * NTHREADS]);
  }
  // vec4 remainder (1-deep grid-stride)
  for (int i = rem_start + blockIdx.x * NTHREADS + threadIdx.x; i < n4;
       i += NBLOCKS * NTHREADS) {
    fvec4 w = __builtin_nontemporal_load(&x4[i]);
    __builtin_nontemporal_store(quant4(w), &o4[i]);
  }
  // scalar tail (N divisible by 4; kept for safety)
  for (int k = n4 * 4 + blockIdx.x * NTHREADS + threadIdx.x; k < n;
       k += NBLOCKS * NTHREADS) {
    out[k] = quant(x[k]);
  }
}

// ---- K3: final reduce + 2x2 solve — unchanged from round 8 ----
__global__ __launch_bounds__(NTHREADS) void lq_final(
    const float* __restrict__ partials, const float* __restrict__ basis,
    float* __restrict__ out_basis, int n, int nparts) {
  double C0 = 0, C1 = 0, C2 = 0, SW = 0, SW0 = 0, SW1 = 0, SW2 = 0;
  for (int i = threadIdx.x; i < nparts; i += blockDim.x) {
    C0 += (double)partials[7 * i + 0];
    C1 += (double)partials[7 * i + 1];
    C2 += (double)partials[7 * i + 2];
    SW += (double)partials[7 * i + 3];
    SW0 += (double)partials[7 * i + 4];
    SW1 += (double)partials[7 * i + 5];
    SW2 += (double)partials[7 * i + 6];
  }
  for (int off = 32; off; off >>= 1) {
    C0 += __shfl_down(C0, off);
    C1 += __shfl_down(C1, off);
    C2 += __shfl_down(C2, off);
    SW += __shfl_down(SW, off);
    SW0 += __shfl_down(SW0, off);
    SW1 += __shfl_down(SW1, off);
    SW2 += __shfl_down(SW2, off);
  }
  __shared__ double red[7][NTHREADS / 64];
  const int lane = threadIdx.x & 63;
  const int wid = threadIdx.x >> 6;
  if (lane == 0) {
    red[0][wid] = C0;
    red[1][wid] = C1;
    red[2][wid] = C2;
    red[3][wid] = SW;
    red[4][wid] = SW0;
    red[5][wid] = SW1;
    red[6][wid] = SW2;
  }
  __syncthreads();
  if (threadIdx.x == 0) {
    double c0 = 0, c1 = 0, c2 = 0, s = 0, s0 = 0, s1 = 0, s2 = 0;
#pragma unroll
    for (int w = 0; w < NTHREADS / 64; ++w) {
      c0 += red[0][w];
      c1 += red[1][w];
      c2 += red[2][w];
      s += red[3][w];
      s0 += red[4][w];
      s1 += red[5][w];
      s2 += red[6][w];
    }
    const float v0 = basis[0], v1 = basis[1];
    float lev[4] = {-v0 - v1, -v0 + v1, v0 - v1, v0 + v1};
    float e0[4] = {-1.f, -1.f, 1.f, 1.f};
    float e1[4] = {-1.f, 1.f, -1.f, 1.f};
#define CSWAP(i, j)                                                   \
    if (lev[i] > lev[j]) {                                            \
      float t = lev[i]; lev[i] = lev[j]; lev[j] = t;                  \
      t = e0[i]; e0[i] = e0[j]; e0[j] = t;                            \
      t = e1[i]; e1[i] = e1[j]; e1[j] = t;                            \
    }
    CSWAP(0, 1) CSWAP(2, 3) CSWAP(0, 2) CSWAP(1, 3) CSWAP(1, 2)
#undef CSWAP
    const double A0 = e0[0], A1 = e0[1], A2 = e0[2], A3 = e0[3];
    const double B0 = e1[0], B1 = e1[1], B2 = e1[2], B3 = e1[3];
    const double N = (double)n;
    // telescoped sums over the monotone one-hot
    const double Sb0 = A0 * s + (A1 - A0) * s0 + (A2 - A1) * s1 + (A3 - A2) * s2;
    const double Sb1 = B0 * s + (B1 - B0) * s0 + (B2 - B1) * s1 + (B3 - B2) * s2;
    const double P0 = A0 * B0, P1 = A1 * B1, P2 = A2 * B2, P3 = A3 * B3;
    const double S01 = P0 * N + (P1 - P0) * c0 + (P2 - P1) * c1 + (P3 - P2) * c2;
    const double det = N * N - S01 * S01;
    const double nv0 = (N * Sb0 - S01 * Sb1) / det;
    const double nv1 = (N * Sb1 - S01 * Sb0) / det;
    out_basis[0] = (float)(0.9 * (double)v0 + 0.1 * nv0);
    out_basis[1] = (float)(0.9 * (double)v1 + 0.1 * nv1);
  }
}

extern "C" void kernel_launch(void* const* d_in, const int* in_sizes, int n_in,
                              void* d_out, int out_size, void* d_ws, size_t ws_size,
                              hipStream_t stream) {
  const float* x = (const float*)d_in[0];
  const float* basis = (const float*)d_in[1];
  float* out = (float*)d_out;
  const int n = in_sizes[0];
  float* partials = (float*)d_ws;  // nblocks * 7 floats

  int nblocks = NBLOCKS;
  const int maxb = (int)(ws_size / (7 * sizeof(float)));
  if (nblocks > maxb) nblocks = maxb;
  if (nblocks < 1) nblocks = 1;

  const int n4 = n / 4;
  lq_stats<<<nblocks, NTHREADS, 0, stream>>>(x, basis, partials, n4);
  lq_quant<<<NBLOCKS, NTHREADS, 0, stream>>>(x, basis, out, n, n4);
  lq_final<<<1, NTHREADS, 0, stream>>>(partials, basis, out + n, n, nblocks);
}